// Round 13
// baseline (680.550 us; speedup 1.0000x reference)
//
#include <hip/hip_runtime.h>
#include <hip/hip_bf16.h>

typedef unsigned short u16;
typedef __bf16 bf16x8 __attribute__((ext_vector_type(8)));
typedef float f32x4 __attribute__((ext_vector_type(4)));

#define D_MODEL 2048
#define D_FF    8192
#define NH      16
#define HD      128
#define BATCH   2
#define SEQ     2048
#define ROWS    (BATCH*SEQ)   // 4096

__device__ __forceinline__ u16 f2bf(float f) {
  union { __hip_bfloat16 h; u16 u; } cv;
  cv.h = __float2bfloat16(f);
  return cv.u;
}

__device__ __forceinline__ void gload16(const u16* g, u16* l) {
  __builtin_amdgcn_global_load_lds((const __attribute__((address_space(1))) void*)g,
                                   (__attribute__((address_space(3))) void*)l,
                                   16, 0, 0);
}

__device__ __forceinline__ float gelu_f(float x) {
  const float k0 = 0.7978845608028654f, k1 = 0.044715f;
  return 0.5f * x * (1.0f + tanhf(k0 * (x + k1 * x * x * x)));
}

// ---------------- LayerNorm: fp32 [rows][2048] -> bf16 [rows][2048] ----------
__global__ __launch_bounds__(256) void ln_bf16_kernel(
    const float* __restrict__ x, const float* __restrict__ sc,
    const float* __restrict__ bs, u16* __restrict__ out)
{
  __shared__ float red[8];
  const int row = blockIdx.x, t = threadIdx.x;
  const int w = t >> 6, l = t & 63;
  const float* xr = x + (size_t)row * D_MODEL;
  float4 a = ((const float4*)xr)[t*2];
  float4 b = ((const float4*)xr)[t*2+1];
  float s  = a.x+a.y+a.z+a.w + b.x+b.y+b.z+b.w;
  float s2 = a.x*a.x+a.y*a.y+a.z*a.z+a.w*a.w + b.x*b.x+b.y*b.y+b.z*b.z+b.w*b.w;
  for (int off = 32; off; off >>= 1) { s += __shfl_down(s, off); s2 += __shfl_down(s2, off); }
  if (l == 0) { red[w] = s; red[4+w] = s2; }
  __syncthreads();
  s  = red[0]+red[1]+red[2]+red[3];
  s2 = red[4]+red[5]+red[6]+red[7];
  const float mu  = s * (1.0f / D_MODEL);
  const float var = s2 * (1.0f / D_MODEL) - mu * mu;
  const float inv = rsqrtf(var + 1e-6f);
  float4 g0 = ((const float4*)sc)[t*2], g1 = ((const float4*)sc)[t*2+1];
  float4 q0 = ((const float4*)bs)[t*2], q1 = ((const float4*)bs)[t*2+1];
  union { u16 u[8]; uint4 v; } o;
  o.u[0] = f2bf((a.x-mu)*inv*g0.x + q0.x);
  o.u[1] = f2bf((a.y-mu)*inv*g0.y + q0.y);
  o.u[2] = f2bf((a.z-mu)*inv*g0.z + q0.z);
  o.u[3] = f2bf((a.w-mu)*inv*g0.w + q0.w);
  o.u[4] = f2bf((b.x-mu)*inv*g1.x + q1.x);
  o.u[5] = f2bf((b.y-mu)*inv*g1.y + q1.y);
  o.u[6] = f2bf((b.z-mu)*inv*g1.z + q1.z);
  o.u[7] = f2bf((b.w-mu)*inv*g1.w + q1.w);
  *(uint4*)(&out[(size_t)row * D_MODEL + t*8]) = o.v;
}

// -------- weight transpose+convert: fp32 [R][C] -> bf16 [C][R], 64x64 tiles --
__global__ __launch_bounds__(256) void transpose_w(
    const float* __restrict__ in, u16* __restrict__ out, int R, int C)
{
  __shared__ float tile[64][65];
  const int t = threadIdx.x;
  const int c0 = blockIdx.x*64, r0 = blockIdx.y*64;
  const int cq = (t & 15) * 4, rb = t >> 4;
#pragma unroll
  for (int i = 0; i < 4; ++i) {
    const float4 v = *(const float4*)&in[(size_t)(r0 + rb + i*16)*C + c0 + cq];
    tile[rb + i*16][cq+0] = v.x; tile[rb + i*16][cq+1] = v.y;
    tile[rb + i*16][cq+2] = v.z; tile[rb + i*16][cq+3] = v.w;
  }
  __syncthreads();
#pragma unroll
  for (int i = 0; i < 4; ++i) {
    const int oc = rb + i*16;
    ushort4 o;
    o.x = f2bf(tile[cq+0][oc]); o.y = f2bf(tile[cq+1][oc]);
    o.z = f2bf(tile[cq+2][oc]); o.w = f2bf(tile[cq+3][oc]);
    *(ushort4*)&out[(size_t)(c0 + oc)*R + r0 + cq] = o;
  }
}

// -------- batched 2048x2048 transpose: 4 weights in one launch (z = which) ---
__global__ __launch_bounds__(256) void transpose_w4(
    const float* __restrict__ s0, const float* __restrict__ s1,
    const float* __restrict__ s2, const float* __restrict__ s3,
    u16* __restrict__ d0, u16* __restrict__ d1,
    u16* __restrict__ d2, u16* __restrict__ d3)
{
  __shared__ float tile[64][65];
  const int z = blockIdx.z;
  const float* in = (z == 0) ? s0 : (z == 1) ? s1 : (z == 2) ? s2 : s3;
  u16* out       = (z == 0) ? d0 : (z == 1) ? d1 : (z == 2) ? d2 : d3;
  const int t = threadIdx.x;
  const int c0 = blockIdx.x*64, r0 = blockIdx.y*64;
  const int cq = (t & 15) * 4, rb = t >> 4;
#pragma unroll
  for (int i = 0; i < 4; ++i) {
    const float4 v = *(const float4*)&in[(size_t)(r0 + rb + i*16)*D_MODEL + c0 + cq];
    tile[rb + i*16][cq+0] = v.x; tile[rb + i*16][cq+1] = v.y;
    tile[rb + i*16][cq+2] = v.z; tile[rb + i*16][cq+3] = v.w;
  }
  __syncthreads();
#pragma unroll
  for (int i = 0; i < 4; ++i) {
    const int oc = rb + i*16;
    ushort4 o;
    o.x = f2bf(tile[cq+0][oc]); o.y = f2bf(tile[cq+1][oc]);
    o.z = f2bf(tile[cq+2][oc]); o.w = f2bf(tile[cq+3][oc]);
    *(ushort4*)&out[(size_t)(c0 + oc)*D_MODEL + r0 + cq] = o;
  }
}

// -------- V transpose: qkv v-section [l][hd] -> vt [hd][l], per batch --------
__global__ __launch_bounds__(256) void transpose_v(
    const u16* __restrict__ qkv, u16* __restrict__ vt)
{
  __shared__ u16 tile[32][34];
  const int t = threadIdx.x;
  const int b = blockIdx.z;
  const int c0 = blockIdx.x*32, r0 = blockIdx.y*32; // r = l, c = h*128+d
  const int col = t & 31, rb = t >> 5;
  const u16* inb = qkv + (size_t)b*SEQ*3*D_MODEL + 2*D_MODEL;
#pragma unroll
  for (int i = 0; i < 4; ++i)
    tile[rb+i*8][col] = inb[(size_t)(r0+rb+i*8)*(3*D_MODEL) + c0+col];
  __syncthreads();
  u16* ob = vt + (size_t)b*SEQ*D_MODEL;
#pragma unroll
  for (int i = 0; i < 4; ++i)
    ob[(size_t)(c0+rb+i*8)*SEQ + r0+col] = tile[col][rb+i*8];
}

// =============================================================================
// 4-phase/K-tile pipelined GEMM with OFFSET staging cadence (round-12 best).
// =============================================================================
template<int EPI, int BNP>
__global__ __launch_bounds__(512, 1) void gemm8p(
    const u16* __restrict__ A, const u16* __restrict__ BT,
    void* __restrict__ Cout, const float* __restrict__ bias,
    const float* __restrict__ res, int N, int K, int gridN)
{
  constexpr int GB    = BNP / 128;
  constexpr int NI    = BNP / 64;
  constexpr int BHALF = BNP * 32;
  constexpr int BUFU  = 16384 + BNP * 64;
  __shared__ __align__(16) u16 lds[2 * BUFU];
  const int t = threadIdx.x;
  const int nwg = gridDim.x;
  const int wg = (int)blockIdx.x;
  const int wgid = (wg & 7) * (nwg >> 3) + (wg >> 3);   // XCD swizzle (nwg%8==0)
  const int bx = wgid % gridN, by = wgid / gridN;
  const int m0 = by * 256, n0 = bx * BNP;
  const int w = t >> 6, l = t & 63;
  const int wm = w >> 2, wn = w & 3;
  const int l15 = l & 15, lq = l >> 4;

  const int srow = t >> 2;
  const int c0s  = (t & 3) ^ ((srow >> 1) & 3);
  const u16* aS0 = A  + (size_t)(m0 + srow) * K + c0s * 8;
  const u16* aS1 = A  + (size_t)(m0 + 128 + srow) * K + c0s * 8;
  const u16* bS0 = BT + (size_t)(n0 + srow) * K + c0s * 8;
  const u16* bS1 = BT + (size_t)(n0 + (GB == 2 ? 128 : 0) + srow) * K + c0s * 8;

  int offA_[2][4], offB_[NI];
#pragma unroll
  for (int mq = 0; mq < 2; ++mq)
#pragma unroll
    for (int i2 = 0; i2 < 4; ++i2) {
      const int ra = wm * 128 + mq * 64 + i2 * 16 + l15;
      offA_[mq][i2] = ra * 32 + ((lq ^ ((ra >> 1) & 3)) * 8);
    }
#pragma unroll
  for (int j = 0; j < NI; ++j) {
    const int rb = wn * (BNP / 4) + j * 16 + l15;
    offB_[j] = rb * 32 + ((lq ^ ((rb >> 1) & 3)) * 8);
  }

  f32x4 acc[8][NI] = {};
  bf16x8 bfv[NI];
  const int nt = K >> 6;

#define STAGE_A(dst, Tn, kh) { \
    gload16(aS0 + (size_t)(Tn)*64 + (kh)*32, (dst) + (kh)*8192 + t*8); \
    gload16(aS1 + (size_t)(Tn)*64 + (kh)*32, (dst) + (kh)*8192 + 4096 + t*8); }
#define STAGE_B(dst, Tn, kh) { \
    gload16(bS0 + (size_t)(Tn)*64 + (kh)*32, (dst) + 16384 + (kh)*BHALF + t*8); \
    if (GB == 2) gload16(bS1 + (size_t)(Tn)*64 + (kh)*32, (dst) + 16384 + (kh)*BHALF + 4096 + t*8); }
#define VMS { if (GB == 2) { asm volatile("s_waitcnt vmcnt(4)" ::: "memory"); } \
              else        { asm volatile("s_waitcnt vmcnt(3)" ::: "memory"); } \
              __builtin_amdgcn_sched_barrier(0); }
#define VM0 { asm volatile("s_waitcnt vmcnt(0)" ::: "memory"); __builtin_amdgcn_sched_barrier(0); }
#define NOP { }

#define PHASE(bufc, MQ, KH, DOB, STAGECODE, WAITCODE) { \
    bf16x8 af_[4]; \
    _Pragma("unroll") \
    for (int i2 = 0; i2 < 4; ++i2) \
      af_[i2] = *(const bf16x8*)&(bufc)[offA_[MQ][i2] + (KH)*8192]; \
    if (DOB) { \
      _Pragma("unroll") \
      for (int j = 0; j < NI; ++j) \
        bfv[j] = *(const bf16x8*)&(bufc)[offB_[j] + 16384 + (KH)*BHALF]; \
    } \
    STAGECODE; \
    __builtin_amdgcn_s_barrier(); \
    asm volatile("s_waitcnt lgkmcnt(0)" ::: "memory"); \
    __builtin_amdgcn_sched_barrier(0); \
    __builtin_amdgcn_s_setprio(1); \
    _Pragma("unroll") \
    for (int i2 = 0; i2 < 4; ++i2) \
      _Pragma("unroll") \
      for (int j = 0; j < NI; ++j) \
        acc[(MQ)*4 + i2][j] = __builtin_amdgcn_mfma_f32_16x16x32_bf16(af_[i2], bfv[j], acc[(MQ)*4 + i2][j], 0, 0, 0); \
    __builtin_amdgcn_s_setprio(0); \
    WAITCODE; \
    __builtin_amdgcn_s_barrier(); }

  {
    u16* b0p = lds;
    u16* b1p = &lds[BUFU];
    STAGE_A(b0p, 0, 0); STAGE_B(b0p, 0, 0); STAGE_A(b0p, 0, 1); STAGE_B(b0p, 0, 1);
    STAGE_A(b1p, 1, 0); STAGE_B(b1p, 1, 0);
  }
  VMS;
  __builtin_amdgcn_s_barrier();

  for (int T = 0; T < nt - 2; ++T) {
    u16* bufc = &lds[(T & 1) * BUFU];
    u16* bufn = &lds[((T + 1) & 1) * BUFU];
    PHASE(bufc, 0, 0, 1, STAGE_A(bufn, T + 1, 1), NOP);
    PHASE(bufc, 1, 0, 0, STAGE_B(bufn, T + 1, 1), VMS);
    PHASE(bufc, 0, 1, 1, STAGE_A(bufc, T + 2, 0), NOP);
    PHASE(bufc, 1, 1, 0, STAGE_B(bufc, T + 2, 0), NOP);
  }
  {
    u16* bufc = &lds[((nt - 2) & 1) * BUFU];
    u16* bufn = &lds[((nt - 1) & 1) * BUFU];
    PHASE(bufc, 0, 0, 1, STAGE_A(bufn, nt - 1, 1), NOP);
    PHASE(bufc, 1, 0, 0, STAGE_B(bufn, nt - 1, 1), VMS);
    PHASE(bufc, 0, 1, 1, NOP, NOP);
    PHASE(bufc, 1, 1, 0, NOP, VM0);
  }
  {
    u16* bufc = &lds[((nt - 1) & 1) * BUFU];
    PHASE(bufc, 0, 0, 1, NOP, NOP);
    PHASE(bufc, 1, 0, 0, NOP, NOP);
    PHASE(bufc, 0, 1, 1, NOP, NOP);
    PHASE(bufc, 1, 1, 0, NOP, NOP);
  }
#undef PHASE
#undef STAGE_A
#undef STAGE_B
#undef VMS
#undef VM0
#undef NOP

  const int rowb = m0 + wm * 128;
  const int colb = n0 + wn * (BNP / 4);
#pragma unroll
  for (int mi = 0; mi < 8; ++mi) {
#pragma unroll
    for (int ni = 0; ni < NI; ++ni) {
      const int col = colb + ni * 16 + l15;
      const int row0 = rowb + mi * 16 + lq * 4;
      float bv = (EPI == 2 || EPI == 3) ? bias[col] : 0.f;
#pragma unroll
      for (int r = 0; r < 4; ++r) {
        const float v = acc[mi][ni][r];
        const size_t idx = (size_t)(row0 + r) * N + col;
        if (EPI == 0)      ((u16*)Cout)[idx] = f2bf(v);
        else if (EPI == 1) ((float*)Cout)[idx] = v + res[idx];
        else if (EPI == 2) ((u16*)Cout)[idx] = f2bf(gelu_f(v + bv));
        else               ((float*)Cout)[idx] = v + bv + res[idx];
      }
    }
  }
}

// =============================================================================
// Causal flash attention, KVBLK=128, shared-prefix staging for paired q-tiles.
// grid: (B*NH)*16; block i serves qt=i (S) and qt=31-i (L). K/V tiles are
// staged ONCE per 128-block and consumed by both q-tiles (S's range nests in
// L's). LDS: K 32KB + V 32KB + P 16KB = 80KB -> 2 blocks/CU.
// Compute pattern identical to the verified 64-wide version (widths doubled).
// =============================================================================
__global__ __launch_bounds__(256) void attn_kernel(
    const u16* __restrict__ qkv, const u16* __restrict__ vt,
    u16* __restrict__ out)
{
  __shared__ u16 Ks[128*128];   // [k][hd]
  __shared__ u16 Vs[128*128];   // [hd][kv]
  __shared__ u16 Ps[4*16*128];  // per-wave 16 q x 128 k
  const int t = threadIdx.x;
  const int pairi = blockIdx.x & 15, bh = blockIdx.x >> 4;
  const int b = bh >> 4, h = bh & 15;
  const int w = t >> 6, l = t & 63;
  const int l15 = l & 15, lq = l >> 4;
  const size_t kbase = (size_t)b*SEQ*(3*D_MODEL) + D_MODEL + h*HD;
  const size_t vbase = (size_t)(b*SEQ + h*HD) * SEQ;
  u16* pw = &Ps[w*2048];

  const int qtS = pairi, qtL = 31 - pairi;
  const int jmaxS = qtS >> 1, jmaxL = qtL >> 1;
  const float scale = 0.08838834764831845f; // 1/sqrt(128)

  bf16x8 qfS[4], qfL[4];
  {
    const u16* qbS = qkv + (size_t)(b*SEQ + qtS*64 + w*16 + l15)*(3*D_MODEL) + h*HD;
    const u16* qbL = qkv + (size_t)(b*SEQ + qtL*64 + w*16 + l15)*(3*D_MODEL) + h*HD;
#pragma unroll
    for (int kk = 0; kk < 4; ++kk) {
      qfS[kk] = *(const bf16x8*)(qbS + kk*32 + lq*8);
      qfL[kk] = *(const bf16x8*)(qbL + kk*32 + lq*8);
    }
  }
  float mS[4], mL[4], lsS[4], lsL[4];
#pragma unroll
  for (int r = 0; r < 4; ++r) { mS[r] = -INFINITY; mL[r] = -INFINITY; lsS[r] = 0.f; lsL[r] = 0.f; }
  f32x4 accS[8] = {}, accL[8] = {};

  // per-(qt) tile compute: QK^T (8x4 MFMA) -> mask/scale -> online softmax ->
  // P to wave-private LDS (swizzled) -> PV (4x8 MFMA). Same as verified 64-wide.
#define COMPUTE(QT, JMAX, QF, MM, LS, ACC) { \
    f32x4 sacc[8]; \
    _Pragma("unroll") \
    for (int nf = 0; nf < 8; ++nf) sacc[nf] = (f32x4){0.f,0.f,0.f,0.f}; \
    _Pragma("unroll") \
    for (int nf = 0; nf < 8; ++nf) { \
      const int kr = nf*16 + l15; \
      const int sw = kr & 7; \
      _Pragma("unroll") \
      for (int kk = 0; kk < 4; ++kk) { \
        bf16x8 kf = *(const bf16x8*)&Ks[kr*128 + ((kk*4+lq) ^ sw)*8]; \
        sacc[nf] = __builtin_amdgcn_mfma_f32_16x16x32_bf16(QF[kk], kf, sacc[nf], 0, 0, 0); \
      } \
    } \
    if (j == (JMAX)) { \
      _Pragma("unroll") \
      for (int nf = 0; nf < 8; ++nf) \
        _Pragma("unroll") \
        for (int r = 0; r < 4; ++r) { \
          float s = sacc[nf][r] * scale; \
          const int ki = j*128 + nf*16 + l15; \
          const int qi = (QT)*64 + w*16 + lq*4 + r; \
          if (ki > qi) s = -100000.0f; \
          sacc[nf][r] = s; \
        } \
    } else { \
      _Pragma("unroll") \
      for (int nf = 0; nf < 8; ++nf) \
        _Pragma("unroll") \
        for (int r = 0; r < 4; ++r) sacc[nf][r] *= scale; \
    } \
    float scal[4]; \
    _Pragma("unroll") \
    for (int r = 0; r < 4; ++r) { \
      float mx = sacc[0][r]; \
      _Pragma("unroll") \
      for (int nf = 1; nf < 8; ++nf) mx = fmaxf(mx, sacc[nf][r]); \
      _Pragma("unroll") \
      for (int off = 1; off < 16; off <<= 1) mx = fmaxf(mx, __shfl_xor(mx, off)); \
      const float mn = fmaxf(MM[r], mx); \
      scal[r] = __expf(MM[r] - mn); \
      MM[r] = mn; \
      float rs = 0.f; \
      _Pragma("unroll") \
      for (int nf = 0; nf < 8; ++nf) { \
        const float p = __expf(sacc[nf][r] - mn); \
        sacc[nf][r] = p; \
        rs += p; \
      } \
      _Pragma("unroll") \
      for (int off = 1; off < 16; off <<= 1) rs += __shfl_xor(rs, off); \
      LS[r] = LS[r]*scal[r] + rs; \
    } \
    _Pragma("unroll") \
    for (int nf2 = 0; nf2 < 8; ++nf2) \
      _Pragma("unroll") \
      for (int r = 0; r < 4; ++r) ACC[nf2][r] *= scal[r]; \
    _Pragma("unroll") \
    for (int nf = 0; nf < 8; ++nf) \
      _Pragma("unroll") \
      for (int r = 0; r < 4; ++r) { \
        const int qr = lq*4 + r, kc = nf*16 + l15; \
        pw[qr*128 + (((kc>>3) ^ (qr&7))*8 + (kc&7))] = f2bf(sacc[nf][r]); \
      } \
    _Pragma("unroll") \
    for (int kk2 = 0; kk2 < 4; ++kk2) { \
      bf16x8 pf = *(const bf16x8*)&pw[l15*128 + (((kk2*4+lq) ^ (l15&7))*8)]; \
      _Pragma("unroll") \
      for (int nf2 = 0; nf2 < 8; ++nf2) { \
        const int vr = nf2*16 + l15; \
        bf16x8 vf = *(const bf16x8*)&Vs[vr*128 + ((kk2*4+lq) ^ (vr&7))*8]; \
        ACC[nf2] = __builtin_amdgcn_mfma_f32_16x16x32_bf16(pf, vf, ACC[nf2], 0, 0, 0); \
      } \
    } }

  for (int j = 0; j <= jmaxL; ++j) {
    __syncthreads();
#pragma unroll
    for (int i = 0; i < 8; ++i) {
      const int o16 = i*256 + t;               // 0..2047
      const int row = o16 >> 4, cs = o16 & 15;
      const int srcc = cs ^ (row & 7);
      gload16(qkv + kbase + (size_t)(j*128+row)*(3*D_MODEL) + srcc*8, &Ks[o16*8]);
    }
#pragma unroll
    for (int i = 0; i < 8; ++i) {
      const int o16 = i*256 + t;
      const int row = o16 >> 4, cs = o16 & 15;
      const int srcc = cs ^ (row & 7);
      gload16(vt + vbase + (size_t)row*SEQ + j*128 + srcc*8, &Vs[o16*8]);
    }
    __syncthreads();

    COMPUTE(qtL, jmaxL, qfL, mL, lsL, accL);
    if (j <= jmaxS) COMPUTE(qtS, jmaxS, qfS, mS, lsS, accS);
  }
#undef COMPUTE

  {
    const size_t ro = (size_t)(b*SEQ + qtL*64 + w*16 + lq*4);
#pragma unroll
    for (int r = 0; r < 4; ++r) {
      const float inv = 1.0f / lsL[r];
#pragma unroll
      for (int nf2 = 0; nf2 < 8; ++nf2)
        out[(ro + r)*D_MODEL + h*HD + nf2*16 + l15] = f2bf(accL[nf2][r] * inv);
    }
  }
  {
    const size_t ro = (size_t)(b*SEQ + qtS*64 + w*16 + lq*4);
#pragma unroll
    for (int r = 0; r < 4; ++r) {
      const float inv = 1.0f / lsS[r];
#pragma unroll
      for (int nf2 = 0; nf2 < 8; ++nf2)
        out[(ro + r)*D_MODEL + h*HD + nf2*16 + l15] = f2bf(accS[nf2][r] * inv);
    }
  }
}

// -----------------------------------------------------------------------------
extern "C" void kernel_launch(void* const* d_in, const int* in_sizes, int n_in,
                              void* d_out, int out_size, void* d_ws, size_t ws_size,
                              hipStream_t stream)
{
  (void)in_sizes; (void)n_in; (void)out_size; (void)ws_size;
  const float* x    = (const float*)d_in[0];
  const float* ln1s = (const float*)d_in[2];
  const float* ln1b = (const float*)d_in[3];
  const float* wq   = (const float*)d_in[4];
  const float* wk   = (const float*)d_in[5];
  const float* wv   = (const float*)d_in[6];
  const float* wo   = (const float*)d_in[7];
  const float* ln2s = (const float*)d_in[8];
  const float* ln2b = (const float*)d_in[9];
  const float* w1   = (const float*)d_in[10];
  const float* b1   = (const float*)d_in[11];
  const float* w2   = (const float*)d_in[12];
  const float* b2   = (const float*)d_in[13];
  float* out = (float*)d_out;

  char* ws = (char*)d_ws;
  constexpr size_t OFF_WQKV = 0;
  constexpr size_t OFF_WO   = OFF_WQKV + (size_t)3*D_MODEL*D_MODEL*2;
  constexpr size_t OFF_W1   = OFF_WO   + (size_t)D_MODEL*D_MODEL*2;
  constexpr size_t OFF_W2   = OFF_W1   + (size_t)D_FF*D_MODEL*2;
  constexpr size_t OFF_H    = OFF_W2   + (size_t)D_MODEL*D_FF*2;
  constexpr size_t OFF_QKV  = OFF_H    + (size_t)ROWS*D_MODEL*2;
  constexpr size_t OFF_VT   = OFF_QKV  + (size_t)ROWS*3*D_MODEL*2;
  constexpr size_t OFF_ATTN = OFF_VT   + (size_t)ROWS*D_MODEL*2;
  constexpr size_t OFF_X2   = OFF_ATTN + (size_t)ROWS*D_MODEL*2;

  u16*   wqkv_bt = (u16*)(ws + OFF_WQKV);   // [6144][2048]
  u16*   wo_bt   = (u16*)(ws + OFF_WO);     // [2048][2048]
  u16*   w1_bt   = (u16*)(ws + OFF_W1);     // [8192][2048]
  u16*   w2_bt   = (u16*)(ws + OFF_W2);     // [2048][8192]
  u16*   h_bf    = (u16*)(ws + OFF_H);      // [4096][2048]
  u16*   qkv     = (u16*)(ws + OFF_QKV);    // [4096][6144]
  u16*   vt      = (u16*)(ws + OFF_VT);     // [2][2048][2048]
  u16*   act     = qkv;                     // reuse qkv+vt region: [4096][8192]
  u16*   attn    = (u16*)(ws + OFF_ATTN);   // [4096][2048]
  float* x2      = (float*)(ws + OFF_X2);   // [4096][2048]

  const dim3 B256(256), B512(512);

  transpose_w4<<<dim3(32,32,4), B256, 0, stream>>>(
      wq, wk, wv, wo,
      wqkv_bt, wqkv_bt + (size_t)D_MODEL*D_MODEL, wqkv_bt + (size_t)2*D_MODEL*D_MODEL, wo_bt);
  transpose_w<<<dim3(128,32), B256, 0, stream>>>(w1, w1_bt, D_MODEL, D_FF);
  transpose_w<<<dim3(32,128), B256, 0, stream>>>(w2, w2_bt, D_FF, D_MODEL);

  // LN1
  ln_bf16_kernel<<<ROWS, B256, 0, stream>>>(x, ln1s, ln1b, h_bf);
  // QKV: [4096,2048] x [2048,6144] -> bf16  (BN=128, grid 48x16 = 768)
  gemm8p<0,128><<<dim3(768), B512, 0, stream>>>(h_bf, wqkv_bt, qkv, nullptr, nullptr, 3*D_MODEL, D_MODEL, 48);
  // V -> V^T per (b,h)
  transpose_v<<<dim3(64,64,2), B256, 0, stream>>>(qkv, vt);
  // causal flash attention (paired q-tiles, shared-prefix KVBLK=128, grid 512)
  attn_kernel<<<dim3(BATCH*NH*16), B256, 0, stream>>>(qkv, vt, attn);
  // out projection + residual -> x2 fp32  (BN=128, grid 16x16 = 256)
  gemm8p<1,128><<<dim3(256), B512, 0, stream>>>(attn, wo_bt, (void*)x2, nullptr, x, D_MODEL, D_MODEL, 16);
  // LN2
  ln_bf16_kernel<<<ROWS, B256, 0, stream>>>(x2, ln2s, ln2b, h_bf);
  // FFN up + GELU  (BN=256, grid 32x16 = 512)
  gemm8p<2,256><<<dim3(512), B512, 0, stream>>>(h_bf, w1_bt, act, b1, nullptr, D_FF, D_MODEL, 32);
  // FFN down + bias + residual -> out fp32  (BN=128, grid 16x16 = 256)
  gemm8p<3,128><<<dim3(256), B512, 0, stream>>>(act, w2_bt, (void*)out, b2, x2, D_MODEL, D_FF, 16);
}

// Round 14
// 648.373 us; speedup vs baseline: 1.0496x; 1.0496x over previous
//
#include <hip/hip_runtime.h>
#include <hip/hip_bf16.h>

typedef unsigned short u16;
typedef __bf16 bf16x8 __attribute__((ext_vector_type(8)));
typedef float f32x4 __attribute__((ext_vector_type(4)));

#define D_MODEL 2048
#define D_FF    8192
#define NH      16
#define HD      128
#define BATCH   2
#define SEQ     2048
#define ROWS    (BATCH*SEQ)   // 4096

__device__ __forceinline__ u16 f2bf(float f) {
  union { __hip_bfloat16 h; u16 u; } cv;
  cv.h = __float2bfloat16(f);
  return cv.u;
}

__device__ __forceinline__ void gload16(const u16* g, u16* l) {
  __builtin_amdgcn_global_load_lds((const __attribute__((address_space(1))) void*)g,
                                   (__attribute__((address_space(3))) void*)l,
                                   16, 0, 0);
}

__device__ __forceinline__ float gelu_f(float x) {
  const float k0 = 0.7978845608028654f, k1 = 0.044715f;
  return 0.5f * x * (1.0f + tanhf(k0 * (x + k1 * x * x * x)));
}

// ---------------- LayerNorm: fp32 [rows][2048] -> bf16 [rows][2048] ----------
__global__ __launch_bounds__(256) void ln_bf16_kernel(
    const float* __restrict__ x, const float* __restrict__ sc,
    const float* __restrict__ bs, u16* __restrict__ out)
{
  __shared__ float red[8];
  const int row = blockIdx.x, t = threadIdx.x;
  const int w = t >> 6, l = t & 63;
  const float* xr = x + (size_t)row * D_MODEL;
  float4 a = ((const float4*)xr)[t*2];
  float4 b = ((const float4*)xr)[t*2+1];
  float s  = a.x+a.y+a.z+a.w + b.x+b.y+b.z+b.w;
  float s2 = a.x*a.x+a.y*a.y+a.z*a.z+a.w*a.w + b.x*b.x+b.y*b.y+b.z*b.z+b.w*b.w;
  for (int off = 32; off; off >>= 1) { s += __shfl_down(s, off); s2 += __shfl_down(s2, off); }
  if (l == 0) { red[w] = s; red[4+w] = s2; }
  __syncthreads();
  s  = red[0]+red[1]+red[2]+red[3];
  s2 = red[4]+red[5]+red[6]+red[7];
  const float mu  = s * (1.0f / D_MODEL);
  const float var = s2 * (1.0f / D_MODEL) - mu * mu;
  const float inv = rsqrtf(var + 1e-6f);
  float4 g0 = ((const float4*)sc)[t*2], g1 = ((const float4*)sc)[t*2+1];
  float4 q0 = ((const float4*)bs)[t*2], q1 = ((const float4*)bs)[t*2+1];
  union { u16 u[8]; uint4 v; } o;
  o.u[0] = f2bf((a.x-mu)*inv*g0.x + q0.x);
  o.u[1] = f2bf((a.y-mu)*inv*g0.y + q0.y);
  o.u[2] = f2bf((a.z-mu)*inv*g0.z + q0.z);
  o.u[3] = f2bf((a.w-mu)*inv*g0.w + q0.w);
  o.u[4] = f2bf((b.x-mu)*inv*g1.x + q1.x);
  o.u[5] = f2bf((b.y-mu)*inv*g1.y + q1.y);
  o.u[6] = f2bf((b.z-mu)*inv*g1.z + q1.z);
  o.u[7] = f2bf((b.w-mu)*inv*g1.w + q1.w);
  *(uint4*)(&out[(size_t)row * D_MODEL + t*8]) = o.v;
}

// -------- weight transpose+convert: fp32 [R][C] -> bf16 [C][R], 64x64 tiles --
__global__ __launch_bounds__(256) void transpose_w(
    const float* __restrict__ in, u16* __restrict__ out, int R, int C)
{
  __shared__ float tile[64][65];
  const int t = threadIdx.x;
  const int c0 = blockIdx.x*64, r0 = blockIdx.y*64;
  const int cq = (t & 15) * 4, rb = t >> 4;
#pragma unroll
  for (int i = 0; i < 4; ++i) {
    const float4 v = *(const float4*)&in[(size_t)(r0 + rb + i*16)*C + c0 + cq];
    tile[rb + i*16][cq+0] = v.x; tile[rb + i*16][cq+1] = v.y;
    tile[rb + i*16][cq+2] = v.z; tile[rb + i*16][cq+3] = v.w;
  }
  __syncthreads();
#pragma unroll
  for (int i = 0; i < 4; ++i) {
    const int oc = rb + i*16;
    ushort4 o;
    o.x = f2bf(tile[cq+0][oc]); o.y = f2bf(tile[cq+1][oc]);
    o.z = f2bf(tile[cq+2][oc]); o.w = f2bf(tile[cq+3][oc]);
    *(ushort4*)&out[(size_t)(c0 + oc)*R + r0 + cq] = o;
  }
}

// -------- batched 2048x2048 transpose: 4 weights in one launch (z = which) ---
__global__ __launch_bounds__(256) void transpose_w4(
    const float* __restrict__ s0, const float* __restrict__ s1,
    const float* __restrict__ s2, const float* __restrict__ s3,
    u16* __restrict__ d0, u16* __restrict__ d1,
    u16* __restrict__ d2, u16* __restrict__ d3)
{
  __shared__ float tile[64][65];
  const int z = blockIdx.z;
  const float* in = (z == 0) ? s0 : (z == 1) ? s1 : (z == 2) ? s2 : s3;
  u16* out       = (z == 0) ? d0 : (z == 1) ? d1 : (z == 2) ? d2 : d3;
  const int t = threadIdx.x;
  const int c0 = blockIdx.x*64, r0 = blockIdx.y*64;
  const int cq = (t & 15) * 4, rb = t >> 4;
#pragma unroll
  for (int i = 0; i < 4; ++i) {
    const float4 v = *(const float4*)&in[(size_t)(r0 + rb + i*16)*D_MODEL + c0 + cq];
    tile[rb + i*16][cq+0] = v.x; tile[rb + i*16][cq+1] = v.y;
    tile[rb + i*16][cq+2] = v.z; tile[rb + i*16][cq+3] = v.w;
  }
  __syncthreads();
#pragma unroll
  for (int i = 0; i < 4; ++i) {
    const int oc = rb + i*16;
    ushort4 o;
    o.x = f2bf(tile[cq+0][oc]); o.y = f2bf(tile[cq+1][oc]);
    o.z = f2bf(tile[cq+2][oc]); o.w = f2bf(tile[cq+3][oc]);
    *(ushort4*)&out[(size_t)(c0 + oc)*D_MODEL + r0 + cq] = o;
  }
}

// -------- V transpose: qkv v-section [l][hd] -> vt [hd][l], per batch --------
__global__ __launch_bounds__(256) void transpose_v(
    const u16* __restrict__ qkv, u16* __restrict__ vt)
{
  __shared__ u16 tile[32][34];
  const int t = threadIdx.x;
  const int b = blockIdx.z;
  const int c0 = blockIdx.x*32, r0 = blockIdx.y*32; // r = l, c = h*128+d
  const int col = t & 31, rb = t >> 5;
  const u16* inb = qkv + (size_t)b*SEQ*3*D_MODEL + 2*D_MODEL;
#pragma unroll
  for (int i = 0; i < 4; ++i)
    tile[rb+i*8][col] = inb[(size_t)(r0+rb+i*8)*(3*D_MODEL) + c0+col];
  __syncthreads();
  u16* ob = vt + (size_t)b*SEQ*D_MODEL;
#pragma unroll
  for (int i = 0; i < 4; ++i)
    ob[(size_t)(c0+rb+i*8)*SEQ + r0+col] = tile[col][rb+i*8];
}

// =============================================================================
// 4-phase/K-tile pipelined GEMM with OFFSET staging cadence (round-12 best).
// =============================================================================
template<int EPI, int BNP>
__global__ __launch_bounds__(512, 1) void gemm8p(
    const u16* __restrict__ A, const u16* __restrict__ BT,
    void* __restrict__ Cout, const float* __restrict__ bias,
    const float* __restrict__ res, int N, int K, int gridN)
{
  constexpr int GB    = BNP / 128;
  constexpr int NI    = BNP / 64;
  constexpr int BHALF = BNP * 32;
  constexpr int BUFU  = 16384 + BNP * 64;
  __shared__ __align__(16) u16 lds[2 * BUFU];
  const int t = threadIdx.x;
  const int nwg = gridDim.x;
  const int wg = (int)blockIdx.x;
  const int wgid = (wg & 7) * (nwg >> 3) + (wg >> 3);   // XCD swizzle (nwg%8==0)
  const int bx = wgid % gridN, by = wgid / gridN;
  const int m0 = by * 256, n0 = bx * BNP;
  const int w = t >> 6, l = t & 63;
  const int wm = w >> 2, wn = w & 3;
  const int l15 = l & 15, lq = l >> 4;

  const int srow = t >> 2;
  const int c0s  = (t & 3) ^ ((srow >> 1) & 3);
  const u16* aS0 = A  + (size_t)(m0 + srow) * K + c0s * 8;
  const u16* aS1 = A  + (size_t)(m0 + 128 + srow) * K + c0s * 8;
  const u16* bS0 = BT + (size_t)(n0 + srow) * K + c0s * 8;
  const u16* bS1 = BT + (size_t)(n0 + (GB == 2 ? 128 : 0) + srow) * K + c0s * 8;

  int offA_[2][4], offB_[NI];
#pragma unroll
  for (int mq = 0; mq < 2; ++mq)
#pragma unroll
    for (int i2 = 0; i2 < 4; ++i2) {
      const int ra = wm * 128 + mq * 64 + i2 * 16 + l15;
      offA_[mq][i2] = ra * 32 + ((lq ^ ((ra >> 1) & 3)) * 8);
    }
#pragma unroll
  for (int j = 0; j < NI; ++j) {
    const int rb = wn * (BNP / 4) + j * 16 + l15;
    offB_[j] = rb * 32 + ((lq ^ ((rb >> 1) & 3)) * 8);
  }

  f32x4 acc[8][NI] = {};
  bf16x8 bfv[NI];
  const int nt = K >> 6;

#define STAGE_A(dst, Tn, kh) { \
    gload16(aS0 + (size_t)(Tn)*64 + (kh)*32, (dst) + (kh)*8192 + t*8); \
    gload16(aS1 + (size_t)(Tn)*64 + (kh)*32, (dst) + (kh)*8192 + 4096 + t*8); }
#define STAGE_B(dst, Tn, kh) { \
    gload16(bS0 + (size_t)(Tn)*64 + (kh)*32, (dst) + 16384 + (kh)*BHALF + t*8); \
    if (GB == 2) gload16(bS1 + (size_t)(Tn)*64 + (kh)*32, (dst) + 16384 + (kh)*BHALF + 4096 + t*8); }
#define VMS { if (GB == 2) { asm volatile("s_waitcnt vmcnt(4)" ::: "memory"); } \
              else        { asm volatile("s_waitcnt vmcnt(3)" ::: "memory"); } \
              __builtin_amdgcn_sched_barrier(0); }
#define VM0 { asm volatile("s_waitcnt vmcnt(0)" ::: "memory"); __builtin_amdgcn_sched_barrier(0); }
#define NOP { }

#define PHASE(bufc, MQ, KH, DOB, STAGECODE, WAITCODE) { \
    bf16x8 af_[4]; \
    _Pragma("unroll") \
    for (int i2 = 0; i2 < 4; ++i2) \
      af_[i2] = *(const bf16x8*)&(bufc)[offA_[MQ][i2] + (KH)*8192]; \
    if (DOB) { \
      _Pragma("unroll") \
      for (int j = 0; j < NI; ++j) \
        bfv[j] = *(const bf16x8*)&(bufc)[offB_[j] + 16384 + (KH)*BHALF]; \
    } \
    STAGECODE; \
    __builtin_amdgcn_s_barrier(); \
    asm volatile("s_waitcnt lgkmcnt(0)" ::: "memory"); \
    __builtin_amdgcn_sched_barrier(0); \
    __builtin_amdgcn_s_setprio(1); \
    _Pragma("unroll") \
    for (int i2 = 0; i2 < 4; ++i2) \
      _Pragma("unroll") \
      for (int j = 0; j < NI; ++j) \
        acc[(MQ)*4 + i2][j] = __builtin_amdgcn_mfma_f32_16x16x32_bf16(af_[i2], bfv[j], acc[(MQ)*4 + i2][j], 0, 0, 0); \
    __builtin_amdgcn_s_setprio(0); \
    WAITCODE; \
    __builtin_amdgcn_s_barrier(); }

  {
    u16* b0p = lds;
    u16* b1p = &lds[BUFU];
    STAGE_A(b0p, 0, 0); STAGE_B(b0p, 0, 0); STAGE_A(b0p, 0, 1); STAGE_B(b0p, 0, 1);
    STAGE_A(b1p, 1, 0); STAGE_B(b1p, 1, 0);
  }
  VMS;
  __builtin_amdgcn_s_barrier();

  for (int T = 0; T < nt - 2; ++T) {
    u16* bufc = &lds[(T & 1) * BUFU];
    u16* bufn = &lds[((T + 1) & 1) * BUFU];
    PHASE(bufc, 0, 0, 1, STAGE_A(bufn, T + 1, 1), NOP);
    PHASE(bufc, 1, 0, 0, STAGE_B(bufn, T + 1, 1), VMS);
    PHASE(bufc, 0, 1, 1, STAGE_A(bufc, T + 2, 0), NOP);
    PHASE(bufc, 1, 1, 0, STAGE_B(bufc, T + 2, 0), NOP);
  }
  {
    u16* bufc = &lds[((nt - 2) & 1) * BUFU];
    u16* bufn = &lds[((nt - 1) & 1) * BUFU];
    PHASE(bufc, 0, 0, 1, STAGE_A(bufn, nt - 1, 1), NOP);
    PHASE(bufc, 1, 0, 0, STAGE_B(bufn, nt - 1, 1), VMS);
    PHASE(bufc, 0, 1, 1, NOP, NOP);
    PHASE(bufc, 1, 1, 0, NOP, VM0);
  }
  {
    u16* bufc = &lds[((nt - 1) & 1) * BUFU];
    PHASE(bufc, 0, 0, 1, NOP, NOP);
    PHASE(bufc, 1, 0, 0, NOP, NOP);
    PHASE(bufc, 0, 1, 1, NOP, NOP);
    PHASE(bufc, 1, 1, 0, NOP, NOP);
  }
#undef PHASE
#undef STAGE_A
#undef STAGE_B
#undef VMS
#undef VM0
#undef NOP

  const int rowb = m0 + wm * 128;
  const int colb = n0 + wn * (BNP / 4);
#pragma unroll
  for (int mi = 0; mi < 8; ++mi) {
#pragma unroll
    for (int ni = 0; ni < NI; ++ni) {
      const int col = colb + ni * 16 + l15;
      const int row0 = rowb + mi * 16 + lq * 4;
      float bv = (EPI == 2 || EPI == 3) ? bias[col] : 0.f;
#pragma unroll
      for (int r = 0; r < 4; ++r) {
        const float v = acc[mi][ni][r];
        const size_t idx = (size_t)(row0 + r) * N + col;
        if (EPI == 0)      ((u16*)Cout)[idx] = f2bf(v);
        else if (EPI == 1) ((float*)Cout)[idx] = v + res[idx];
        else if (EPI == 2) ((u16*)Cout)[idx] = f2bf(gelu_f(v + bv));
        else               ((float*)Cout)[idx] = v + bv + res[idx];
      }
    }
  }
}

// ---------------- causal flash attention (work-paired, round-12 best) ---------
__global__ __launch_bounds__(256) void attn_kernel(
    const u16* __restrict__ qkv, const u16* __restrict__ vt,
    u16* __restrict__ out)
{
  __shared__ u16 Ks[64*128];
  __shared__ u16 Vs[128*64];
  __shared__ u16 Ps[4*16*64];
  const int t = threadIdx.x;
  const int pairi = blockIdx.x & 15, bh = blockIdx.x >> 4;
  const int b = bh >> 4, h = bh & 15;
  const int w = t >> 6, l = t & 63;
  const int l15 = l & 15, lq = l >> 4;
  const size_t kbase = (size_t)b*SEQ*(3*D_MODEL) + D_MODEL + h*HD;
  const size_t vbase = (size_t)(b*SEQ + h*HD) * SEQ;
  u16* pw = &Ps[w*1024];

  for (int qsel = 0; qsel < 2; ++qsel) {
    const int qt = qsel ? (31 - pairi) : pairi;

    bf16x8 qf[4];
    {
      const u16* qb = qkv + (size_t)(b*SEQ + qt*64 + w*16 + l15)*(3*D_MODEL) + h*HD;
#pragma unroll
      for (int kk = 0; kk < 4; ++kk)
        qf[kk] = *(const bf16x8*)(qb + kk*32 + lq*8);
    }
    float m[4]    = {-INFINITY, -INFINITY, -INFINITY, -INFINITY};
    float lsum[4] = {0.f, 0.f, 0.f, 0.f};
    f32x4 acc_o[8] = {};

    for (int j = 0; j <= qt; ++j) {
      __syncthreads();
#pragma unroll
      for (int i = 0; i < 4; ++i) {
        const int o16 = i*256 + t;
        {
          const int row = o16 >> 4, cs = o16 & 15;
          const int srcc = cs ^ (row & 7);
          gload16(qkv + kbase + (size_t)(j*64+row)*(3*D_MODEL) + srcc*8, &Ks[o16*8]);
        }
        {
          const int row = o16 >> 3, cs = o16 & 7;
          const int srcc = cs ^ (row & 7);
          gload16(vt + vbase + (size_t)row*SEQ + j*64 + srcc*8, &Vs[o16*8]);
        }
      }
      __syncthreads();

      f32x4 sacc[4] = {};
#pragma unroll
      for (int nf = 0; nf < 4; ++nf) {
        const int kr = nf*16 + l15;
        const int sw = kr & 7;
#pragma unroll
        for (int kk = 0; kk < 4; ++kk) {
          bf16x8 kf = *(const bf16x8*)&Ks[kr*128 + ((kk*4+lq) ^ sw)*8];
          sacc[nf] = __builtin_amdgcn_mfma_f32_16x16x32_bf16(qf[kk], kf, sacc[nf], 0, 0, 0);
        }
      }

      const float scale = 0.08838834764831845f; // 1/sqrt(128)
      if (j == qt) {
#pragma unroll
        for (int nf = 0; nf < 4; ++nf)
#pragma unroll
          for (int r = 0; r < 4; ++r) {
            float s = sacc[nf][r] * scale;
            const int ki = nf*16 + l15;
            const int qi = w*16 + lq*4 + r;
            if (ki > qi) s = -100000.0f;
            sacc[nf][r] = s;
          }
      } else {
#pragma unroll
        for (int nf = 0; nf < 4; ++nf)
#pragma unroll
          for (int r = 0; r < 4; ++r) sacc[nf][r] *= scale;
      }

      float scal[4];
#pragma unroll
      for (int r = 0; r < 4; ++r) {
        float mx = fmaxf(fmaxf(sacc[0][r], sacc[1][r]), fmaxf(sacc[2][r], sacc[3][r]));
#pragma unroll
        for (int off = 1; off < 16; off <<= 1)
          mx = fmaxf(mx, __shfl_xor(mx, off));
        const float mn = fmaxf(m[r], mx);
        scal[r] = __expf(m[r] - mn);
        m[r] = mn;
        float rs = 0.f;
#pragma unroll
        for (int nf = 0; nf < 4; ++nf) {
          const float p = __expf(sacc[nf][r] - mn);
          sacc[nf][r] = p;
          rs += p;
        }
#pragma unroll
        for (int off = 1; off < 16; off <<= 1)
          rs += __shfl_xor(rs, off);
        lsum[r] = lsum[r]*scal[r] + rs;
      }
#pragma unroll
      for (int nf2 = 0; nf2 < 8; ++nf2)
#pragma unroll
        for (int r = 0; r < 4; ++r) acc_o[nf2][r] *= scal[r];

#pragma unroll
      for (int nf = 0; nf < 4; ++nf)
#pragma unroll
        for (int r = 0; r < 4; ++r) {
          const int qr = lq*4 + r, kc = nf*16 + l15;
          pw[qr*64 + (((kc>>3) ^ (qr&7))*8 + (kc&7))] = f2bf(sacc[nf][r]);
        }

#pragma unroll
      for (int kk2 = 0; kk2 < 2; ++kk2) {
        bf16x8 pf = *(const bf16x8*)&pw[l15*64 + (((kk2*4+lq) ^ (l15&7))*8)];
#pragma unroll
        for (int nf2 = 0; nf2 < 8; ++nf2) {
          const int vr = nf2*16 + l15;
          bf16x8 vf = *(const bf16x8*)&Vs[vr*64 + ((kk2*4+lq) ^ (vr&7))*8];
          acc_o[nf2] = __builtin_amdgcn_mfma_f32_16x16x32_bf16(pf, vf, acc_o[nf2], 0, 0, 0);
        }
      }
    }

    const size_t ro = (size_t)(b*SEQ + qt*64 + w*16 + lq*4);
#pragma unroll
    for (int r = 0; r < 4; ++r) {
      const float inv = 1.0f / lsum[r];
#pragma unroll
      for (int nf2 = 0; nf2 < 8; ++nf2)
        out[(ro + r)*D_MODEL + h*HD + nf2*16 + l15] = f2bf(acc_o[nf2][r] * inv);
    }
    __syncthreads();
  }
}

// -----------------------------------------------------------------------------
extern "C" void kernel_launch(void* const* d_in, const int* in_sizes, int n_in,
                              void* d_out, int out_size, void* d_ws, size_t ws_size,
                              hipStream_t stream)
{
  (void)in_sizes; (void)n_in; (void)out_size; (void)ws_size;
  const float* x    = (const float*)d_in[0];
  const float* ln1s = (const float*)d_in[2];
  const float* ln1b = (const float*)d_in[3];
  const float* wq   = (const float*)d_in[4];
  const float* wk   = (const float*)d_in[5];
  const float* wv   = (const float*)d_in[6];
  const float* wo   = (const float*)d_in[7];
  const float* ln2s = (const float*)d_in[8];
  const float* ln2b = (const float*)d_in[9];
  const float* w1   = (const float*)d_in[10];
  const float* b1   = (const float*)d_in[11];
  const float* w2   = (const float*)d_in[12];
  const float* b2   = (const float*)d_in[13];
  float* out = (float*)d_out;

  char* ws = (char*)d_ws;
  constexpr size_t OFF_WQKV = 0;
  constexpr size_t OFF_WO   = OFF_WQKV + (size_t)3*D_MODEL*D_MODEL*2;
  constexpr size_t OFF_W1   = OFF_WO   + (size_t)D_MODEL*D_MODEL*2;
  constexpr size_t OFF_W2   = OFF_W1   + (size_t)D_FF*D_MODEL*2;
  constexpr size_t OFF_H    = OFF_W2   + (size_t)D_MODEL*D_FF*2;
  constexpr size_t OFF_QKV  = OFF_H    + (size_t)ROWS*D_MODEL*2;
  constexpr size_t OFF_VT   = OFF_QKV  + (size_t)ROWS*3*D_MODEL*2;
  constexpr size_t OFF_ATTN = OFF_VT   + (size_t)ROWS*D_MODEL*2;
  constexpr size_t OFF_X2   = OFF_ATTN + (size_t)ROWS*D_MODEL*2;

  u16*   wqkv_bt = (u16*)(ws + OFF_WQKV);   // [6144][2048]
  u16*   wo_bt   = (u16*)(ws + OFF_WO);     // [2048][2048]
  u16*   w1_bt   = (u16*)(ws + OFF_W1);     // [8192][2048]
  u16*   w2_bt   = (u16*)(ws + OFF_W2);     // [2048][8192]
  u16*   h_bf    = (u16*)(ws + OFF_H);      // [4096][2048]
  u16*   qkv     = (u16*)(ws + OFF_QKV);    // [4096][6144]
  u16*   vt      = (u16*)(ws + OFF_VT);     // [2][2048][2048]
  u16*   act     = qkv;                     // reuse qkv+vt region: [4096][8192]
  u16*   attn    = (u16*)(ws + OFF_ATTN);   // [4096][2048]
  float* x2      = (float*)(ws + OFF_X2);   // [4096][2048]

  const dim3 B256(256), B512(512);

  transpose_w4<<<dim3(32,32,4), B256, 0, stream>>>(
      wq, wk, wv, wo,
      wqkv_bt, wqkv_bt + (size_t)D_MODEL*D_MODEL, wqkv_bt + (size_t)2*D_MODEL*D_MODEL, wo_bt);
  transpose_w<<<dim3(128,32), B256, 0, stream>>>(w1, w1_bt, D_MODEL, D_FF);
  transpose_w<<<dim3(32,128), B256, 0, stream>>>(w2, w2_bt, D_FF, D_MODEL);

  // LN1
  ln_bf16_kernel<<<ROWS, B256, 0, stream>>>(x, ln1s, ln1b, h_bf);
  // QKV: [4096,2048] x [2048,6144] -> bf16  (BN=128, grid 48x16 = 768)
  gemm8p<0,128><<<dim3(768), B512, 0, stream>>>(h_bf, wqkv_bt, qkv, nullptr, nullptr, 3*D_MODEL, D_MODEL, 48);
  // V -> V^T per (b,h)
  transpose_v<<<dim3(64,64,2), B256, 0, stream>>>(qkv, vt);
  // causal flash attention (paired q-tiles, grid 512)
  attn_kernel<<<dim3(BATCH*NH*16), B256, 0, stream>>>(qkv, vt, attn);
  // out projection + residual -> x2 fp32  (BN=128, grid 16x16 = 256)
  gemm8p<1,128><<<dim3(256), B512, 0, stream>>>(attn, wo_bt, (void*)x2, nullptr, x, D_MODEL, D_MODEL, 16);
  // LN2
  ln_bf16_kernel<<<ROWS, B256, 0, stream>>>(x2, ln2s, ln2b, h_bf);
  // FFN up + GELU  (BN=256, grid 32x16 = 512)
  gemm8p<2,256><<<dim3(512), B512, 0, stream>>>(h_bf, w1_bt, act, b1, nullptr, D_FF, D_MODEL, 32);
  // FFN down + bias + residual -> out fp32  (BN=128, grid 16x16 = 256)
  gemm8p<3,128><<<dim3(256), B512, 0, stream>>>(act, w2_bt, (void*)out, b2, x2, D_MODEL, D_FF, 16);
}

// Round 15
// 639.964 us; speedup vs baseline: 1.0634x; 1.0131x over previous
//
#include <hip/hip_runtime.h>
#include <hip/hip_bf16.h>

typedef unsigned short u16;
typedef __bf16 bf16x8 __attribute__((ext_vector_type(8)));
typedef float f32x4 __attribute__((ext_vector_type(4)));

#define D_MODEL 2048
#define D_FF    8192
#define NH      16
#define HD      128
#define BATCH   2
#define SEQ     2048
#define ROWS    (BATCH*SEQ)   // 4096

__device__ __forceinline__ u16 f2bf(float f) {
  union { __hip_bfloat16 h; u16 u; } cv;
  cv.h = __float2bfloat16(f);
  return cv.u;
}

__device__ __forceinline__ void gload16(const u16* g, u16* l) {
  __builtin_amdgcn_global_load_lds((const __attribute__((address_space(1))) void*)g,
                                   (__attribute__((address_space(3))) void*)l,
                                   16, 0, 0);
}

__device__ __forceinline__ float gelu_f(float x) {
  const float k0 = 0.7978845608028654f, k1 = 0.044715f;
  return 0.5f * x * (1.0f + tanhf(k0 * (x + k1 * x * x * x)));
}

// ---------------- LayerNorm: fp32 [rows][2048] -> bf16 [rows][2048] ----------
__global__ __launch_bounds__(256) void ln_bf16_kernel(
    const float* __restrict__ x, const float* __restrict__ sc,
    const float* __restrict__ bs, u16* __restrict__ out)
{
  __shared__ float red[8];
  const int row = blockIdx.x, t = threadIdx.x;
  const int w = t >> 6, l = t & 63;
  const float* xr = x + (size_t)row * D_MODEL;
  float4 a = ((const float4*)xr)[t*2];
  float4 b = ((const float4*)xr)[t*2+1];
  float s  = a.x+a.y+a.z+a.w + b.x+b.y+b.z+b.w;
  float s2 = a.x*a.x+a.y*a.y+a.z*a.z+a.w*a.w + b.x*b.x+b.y*b.y+b.z*b.z+b.w*b.w;
  for (int off = 32; off; off >>= 1) { s += __shfl_down(s, off); s2 += __shfl_down(s2, off); }
  if (l == 0) { red[w] = s; red[4+w] = s2; }
  __syncthreads();
  s  = red[0]+red[1]+red[2]+red[3];
  s2 = red[4]+red[5]+red[6]+red[7];
  const float mu  = s * (1.0f / D_MODEL);
  const float var = s2 * (1.0f / D_MODEL) - mu * mu;
  const float inv = rsqrtf(var + 1e-6f);
  float4 g0 = ((const float4*)sc)[t*2], g1 = ((const float4*)sc)[t*2+1];
  float4 q0 = ((const float4*)bs)[t*2], q1 = ((const float4*)bs)[t*2+1];
  union { u16 u[8]; uint4 v; } o;
  o.u[0] = f2bf((a.x-mu)*inv*g0.x + q0.x);
  o.u[1] = f2bf((a.y-mu)*inv*g0.y + q0.y);
  o.u[2] = f2bf((a.z-mu)*inv*g0.z + q0.z);
  o.u[3] = f2bf((a.w-mu)*inv*g0.w + q0.w);
  o.u[4] = f2bf((b.x-mu)*inv*g1.x + q1.x);
  o.u[5] = f2bf((b.y-mu)*inv*g1.y + q1.y);
  o.u[6] = f2bf((b.z-mu)*inv*g1.z + q1.z);
  o.u[7] = f2bf((b.w-mu)*inv*g1.w + q1.w);
  *(uint4*)(&out[(size_t)row * D_MODEL + t*8]) = o.v;
}

// -------- ALL weight transposes in ONE launch: fp32 [R][C] -> bf16 [C][R] ----
// blocks 0..4095: wq/wk/wv/wo (2048x2048, 1024 tiles each)
// blocks 4096..8191: w1 (2048x8192); blocks 8192..12287: w2 (8192x2048)
__global__ __launch_bounds__(256) void transpose_all(
    const float* __restrict__ wq, const float* __restrict__ wk,
    const float* __restrict__ wv, const float* __restrict__ wo,
    const float* __restrict__ w1, const float* __restrict__ w2,
    u16* __restrict__ wqkv_bt, u16* __restrict__ wo_bt,
    u16* __restrict__ w1_bt, u16* __restrict__ w2_bt)
{
  __shared__ float tile[64][65];
  const int id = (int)blockIdx.x;
  const float* in; u16* out; int R, C, tx, ty;
  if (id < 4096) {
    const int z = id >> 10, tid = id & 1023;
    in  = (z == 0) ? wq : (z == 1) ? wk : (z == 2) ? wv : wo;
    out = (z == 3) ? wo_bt : wqkv_bt + (size_t)z * D_MODEL * D_MODEL;
    R = D_MODEL; C = D_MODEL; tx = tid & 31; ty = tid >> 5;
  } else if (id < 8192) {
    const int tid = id - 4096;
    in = w1; out = w1_bt; R = D_MODEL; C = D_FF; tx = tid & 127; ty = tid >> 7;
  } else {
    const int tid = id - 8192;
    in = w2; out = w2_bt; R = D_FF; C = D_MODEL; tx = tid & 31; ty = tid >> 5;
  }
  const int t = threadIdx.x;
  const int c0 = tx*64, r0 = ty*64;
  const int cq = (t & 15) * 4, rb = t >> 4;
#pragma unroll
  for (int i = 0; i < 4; ++i) {
    const float4 v = *(const float4*)&in[(size_t)(r0 + rb + i*16)*C + c0 + cq];
    tile[rb + i*16][cq+0] = v.x; tile[rb + i*16][cq+1] = v.y;
    tile[rb + i*16][cq+2] = v.z; tile[rb + i*16][cq+3] = v.w;
  }
  __syncthreads();
#pragma unroll
  for (int i = 0; i < 4; ++i) {
    const int oc = rb + i*16;
    ushort4 o;
    o.x = f2bf(tile[cq+0][oc]); o.y = f2bf(tile[cq+1][oc]);
    o.z = f2bf(tile[cq+2][oc]); o.w = f2bf(tile[cq+3][oc]);
    *(ushort4*)&out[(size_t)(c0 + oc)*R + r0 + cq] = o;
  }
}

// -------- V transpose: qkv v-section [l][hd] -> vt [hd][l], per batch --------
__global__ __launch_bounds__(256) void transpose_v(
    const u16* __restrict__ qkv, u16* __restrict__ vt)
{
  __shared__ u16 tile[32][34];
  const int t = threadIdx.x;
  const int b = blockIdx.z;
  const int c0 = blockIdx.x*32, r0 = blockIdx.y*32; // r = l, c = h*128+d
  const int col = t & 31, rb = t >> 5;
  const u16* inb = qkv + (size_t)b*SEQ*3*D_MODEL + 2*D_MODEL;
#pragma unroll
  for (int i = 0; i < 4; ++i)
    tile[rb+i*8][col] = inb[(size_t)(r0+rb+i*8)*(3*D_MODEL) + c0+col];
  __syncthreads();
  u16* ob = vt + (size_t)b*SEQ*D_MODEL;
#pragma unroll
  for (int i = 0; i < 4; ++i)
    ob[(size_t)(c0+rb+i*8)*SEQ + r0+col] = tile[col][rb+i*8];
}

// =============================================================================
// 4-phase/K-tile pipelined GEMM with OFFSET staging cadence (round-12 best).
// =============================================================================
template<int EPI, int BNP>
__global__ __launch_bounds__(512, 1) void gemm8p(
    const u16* __restrict__ A, const u16* __restrict__ BT,
    void* __restrict__ Cout, const float* __restrict__ bias,
    const float* __restrict__ res, int N, int K, int gridN)
{
  constexpr int GB    = BNP / 128;
  constexpr int NI    = BNP / 64;
  constexpr int BHALF = BNP * 32;
  constexpr int BUFU  = 16384 + BNP * 64;
  __shared__ __align__(16) u16 lds[2 * BUFU];
  const int t = threadIdx.x;
  const int nwg = gridDim.x;
  const int wg = (int)blockIdx.x;
  const int wgid = (wg & 7) * (nwg >> 3) + (wg >> 3);   // XCD swizzle (nwg%8==0)
  const int bx = wgid % gridN, by = wgid / gridN;
  const int m0 = by * 256, n0 = bx * BNP;
  const int w = t >> 6, l = t & 63;
  const int wm = w >> 2, wn = w & 3;
  const int l15 = l & 15, lq = l >> 4;

  const int srow = t >> 2;
  const int c0s  = (t & 3) ^ ((srow >> 1) & 3);
  const u16* aS0 = A  + (size_t)(m0 + srow) * K + c0s * 8;
  const u16* aS1 = A  + (size_t)(m0 + 128 + srow) * K + c0s * 8;
  const u16* bS0 = BT + (size_t)(n0 + srow) * K + c0s * 8;
  const u16* bS1 = BT + (size_t)(n0 + (GB == 2 ? 128 : 0) + srow) * K + c0s * 8;

  int offA_[2][4], offB_[NI];
#pragma unroll
  for (int mq = 0; mq < 2; ++mq)
#pragma unroll
    for (int i2 = 0; i2 < 4; ++i2) {
      const int ra = wm * 128 + mq * 64 + i2 * 16 + l15;
      offA_[mq][i2] = ra * 32 + ((lq ^ ((ra >> 1) & 3)) * 8);
    }
#pragma unroll
  for (int j = 0; j < NI; ++j) {
    const int rb = wn * (BNP / 4) + j * 16 + l15;
    offB_[j] = rb * 32 + ((lq ^ ((rb >> 1) & 3)) * 8);
  }

  f32x4 acc[8][NI] = {};
  bf16x8 bfv[NI];
  const int nt = K >> 6;

#define STAGE_A(dst, Tn, kh) { \
    gload16(aS0 + (size_t)(Tn)*64 + (kh)*32, (dst) + (kh)*8192 + t*8); \
    gload16(aS1 + (size_t)(Tn)*64 + (kh)*32, (dst) + (kh)*8192 + 4096 + t*8); }
#define STAGE_B(dst, Tn, kh) { \
    gload16(bS0 + (size_t)(Tn)*64 + (kh)*32, (dst) + 16384 + (kh)*BHALF + t*8); \
    if (GB == 2) gload16(bS1 + (size_t)(Tn)*64 + (kh)*32, (dst) + 16384 + (kh)*BHALF + 4096 + t*8); }
#define VMS { if (GB == 2) { asm volatile("s_waitcnt vmcnt(4)" ::: "memory"); } \
              else        { asm volatile("s_waitcnt vmcnt(3)" ::: "memory"); } \
              __builtin_amdgcn_sched_barrier(0); }
#define VM0 { asm volatile("s_waitcnt vmcnt(0)" ::: "memory"); __builtin_amdgcn_sched_barrier(0); }
#define NOP { }

#define PHASE(bufc, MQ, KH, DOB, STAGECODE, WAITCODE) { \
    bf16x8 af_[4]; \
    _Pragma("unroll") \
    for (int i2 = 0; i2 < 4; ++i2) \
      af_[i2] = *(const bf16x8*)&(bufc)[offA_[MQ][i2] + (KH)*8192]; \
    if (DOB) { \
      _Pragma("unroll") \
      for (int j = 0; j < NI; ++j) \
        bfv[j] = *(const bf16x8*)&(bufc)[offB_[j] + 16384 + (KH)*BHALF]; \
    } \
    STAGECODE; \
    __builtin_amdgcn_s_barrier(); \
    asm volatile("s_waitcnt lgkmcnt(0)" ::: "memory"); \
    __builtin_amdgcn_sched_barrier(0); \
    __builtin_amdgcn_s_setprio(1); \
    _Pragma("unroll") \
    for (int i2 = 0; i2 < 4; ++i2) \
      _Pragma("unroll") \
      for (int j = 0; j < NI; ++j) \
        acc[(MQ)*4 + i2][j] = __builtin_amdgcn_mfma_f32_16x16x32_bf16(af_[i2], bfv[j], acc[(MQ)*4 + i2][j], 0, 0, 0); \
    __builtin_amdgcn_s_setprio(0); \
    WAITCODE; \
    __builtin_amdgcn_s_barrier(); }

  {
    u16* b0p = lds;
    u16* b1p = &lds[BUFU];
    STAGE_A(b0p, 0, 0); STAGE_B(b0p, 0, 0); STAGE_A(b0p, 0, 1); STAGE_B(b0p, 0, 1);
    STAGE_A(b1p, 1, 0); STAGE_B(b1p, 1, 0);
  }
  VMS;
  __builtin_amdgcn_s_barrier();

  for (int T = 0; T < nt - 2; ++T) {
    u16* bufc = &lds[(T & 1) * BUFU];
    u16* bufn = &lds[((T + 1) & 1) * BUFU];
    PHASE(bufc, 0, 0, 1, STAGE_A(bufn, T + 1, 1), NOP);
    PHASE(bufc, 1, 0, 0, STAGE_B(bufn, T + 1, 1), VMS);
    PHASE(bufc, 0, 1, 1, STAGE_A(bufc, T + 2, 0), NOP);
    PHASE(bufc, 1, 1, 0, STAGE_B(bufc, T + 2, 0), NOP);
  }
  {
    u16* bufc = &lds[((nt - 2) & 1) * BUFU];
    u16* bufn = &lds[((nt - 1) & 1) * BUFU];
    PHASE(bufc, 0, 0, 1, STAGE_A(bufn, nt - 1, 1), NOP);
    PHASE(bufc, 1, 0, 0, STAGE_B(bufn, nt - 1, 1), VMS);
    PHASE(bufc, 0, 1, 1, NOP, NOP);
    PHASE(bufc, 1, 1, 0, NOP, VM0);
  }
  {
    u16* bufc = &lds[((nt - 1) & 1) * BUFU];
    PHASE(bufc, 0, 0, 1, NOP, NOP);
    PHASE(bufc, 1, 0, 0, NOP, NOP);
    PHASE(bufc, 0, 1, 1, NOP, NOP);
    PHASE(bufc, 1, 1, 0, NOP, NOP);
  }
#undef PHASE
#undef STAGE_A
#undef STAGE_B
#undef VMS
#undef VM0
#undef NOP

  const int rowb = m0 + wm * 128;
  const int colb = n0 + wn * (BNP / 4);
#pragma unroll
  for (int mi = 0; mi < 8; ++mi) {
#pragma unroll
    for (int ni = 0; ni < NI; ++ni) {
      const int col = colb + ni * 16 + l15;
      const int row0 = rowb + mi * 16 + lq * 4;
      float bv = (EPI == 2 || EPI == 3) ? bias[col] : 0.f;
#pragma unroll
      for (int r = 0; r < 4; ++r) {
        const float v = acc[mi][ni][r];
        const size_t idx = (size_t)(row0 + r) * N + col;
        if (EPI == 0)      ((u16*)Cout)[idx] = f2bf(v);
        else if (EPI == 1) ((float*)Cout)[idx] = v + res[idx];
        else if (EPI == 2) ((u16*)Cout)[idx] = f2bf(gelu_f(v + bv));
        else               ((float*)Cout)[idx] = v + bv + res[idx];
      }
    }
  }
}

// ---------------- causal flash attention (work-paired, round-12 best) ---------
__global__ __launch_bounds__(256) void attn_kernel(
    const u16* __restrict__ qkv, const u16* __restrict__ vt,
    u16* __restrict__ out)
{
  __shared__ u16 Ks[64*128];
  __shared__ u16 Vs[128*64];
  __shared__ u16 Ps[4*16*64];
  const int t = threadIdx.x;
  const int pairi = blockIdx.x & 15, bh = blockIdx.x >> 4;
  const int b = bh >> 4, h = bh & 15;
  const int w = t >> 6, l = t & 63;
  const int l15 = l & 15, lq = l >> 4;
  const size_t kbase = (size_t)b*SEQ*(3*D_MODEL) + D_MODEL + h*HD;
  const size_t vbase = (size_t)(b*SEQ + h*HD) * SEQ;
  u16* pw = &Ps[w*1024];

  for (int qsel = 0; qsel < 2; ++qsel) {
    const int qt = qsel ? (31 - pairi) : pairi;

    bf16x8 qf[4];
    {
      const u16* qb = qkv + (size_t)(b*SEQ + qt*64 + w*16 + l15)*(3*D_MODEL) + h*HD;
#pragma unroll
      for (int kk = 0; kk < 4; ++kk)
        qf[kk] = *(const bf16x8*)(qb + kk*32 + lq*8);
    }
    float m[4]    = {-INFINITY, -INFINITY, -INFINITY, -INFINITY};
    float lsum[4] = {0.f, 0.f, 0.f, 0.f};
    f32x4 acc_o[8] = {};

    for (int j = 0; j <= qt; ++j) {
      __syncthreads();
#pragma unroll
      for (int i = 0; i < 4; ++i) {
        const int o16 = i*256 + t;
        {
          const int row = o16 >> 4, cs = o16 & 15;
          const int srcc = cs ^ (row & 7);
          gload16(qkv + kbase + (size_t)(j*64+row)*(3*D_MODEL) + srcc*8, &Ks[o16*8]);
        }
        {
          const int row = o16 >> 3, cs = o16 & 7;
          const int srcc = cs ^ (row & 7);
          gload16(vt + vbase + (size_t)row*SEQ + j*64 + srcc*8, &Vs[o16*8]);
        }
      }
      __syncthreads();

      f32x4 sacc[4] = {};
#pragma unroll
      for (int nf = 0; nf < 4; ++nf) {
        const int kr = nf*16 + l15;
        const int sw = kr & 7;
#pragma unroll
        for (int kk = 0; kk < 4; ++kk) {
          bf16x8 kf = *(const bf16x8*)&Ks[kr*128 + ((kk*4+lq) ^ sw)*8];
          sacc[nf] = __builtin_amdgcn_mfma_f32_16x16x32_bf16(qf[kk], kf, sacc[nf], 0, 0, 0);
        }
      }

      const float scale = 0.08838834764831845f; // 1/sqrt(128)
      if (j == qt) {
#pragma unroll
        for (int nf = 0; nf < 4; ++nf)
#pragma unroll
          for (int r = 0; r < 4; ++r) {
            float s = sacc[nf][r] * scale;
            const int ki = nf*16 + l15;
            const int qi = w*16 + lq*4 + r;
            if (ki > qi) s = -100000.0f;
            sacc[nf][r] = s;
          }
      } else {
#pragma unroll
        for (int nf = 0; nf < 4; ++nf)
#pragma unroll
          for (int r = 0; r < 4; ++r) sacc[nf][r] *= scale;
      }

      float scal[4];
#pragma unroll
      for (int r = 0; r < 4; ++r) {
        float mx = fmaxf(fmaxf(sacc[0][r], sacc[1][r]), fmaxf(sacc[2][r], sacc[3][r]));
#pragma unroll
        for (int off = 1; off < 16; off <<= 1)
          mx = fmaxf(mx, __shfl_xor(mx, off));
        const float mn = fmaxf(m[r], mx);
        scal[r] = __expf(m[r] - mn);
        m[r] = mn;
        float rs = 0.f;
#pragma unroll
        for (int nf = 0; nf < 4; ++nf) {
          const float p = __expf(sacc[nf][r] - mn);
          sacc[nf][r] = p;
          rs += p;
        }
#pragma unroll
        for (int off = 1; off < 16; off <<= 1)
          rs += __shfl_xor(rs, off);
        lsum[r] = lsum[r]*scal[r] + rs;
      }
#pragma unroll
      for (int nf2 = 0; nf2 < 8; ++nf2)
#pragma unroll
        for (int r = 0; r < 4; ++r) acc_o[nf2][r] *= scal[r];

#pragma unroll
      for (int nf = 0; nf < 4; ++nf)
#pragma unroll
        for (int r = 0; r < 4; ++r) {
          const int qr = lq*4 + r, kc = nf*16 + l15;
          pw[qr*64 + (((kc>>3) ^ (qr&7))*8 + (kc&7))] = f2bf(sacc[nf][r]);
        }

#pragma unroll
      for (int kk2 = 0; kk2 < 2; ++kk2) {
        bf16x8 pf = *(const bf16x8*)&pw[l15*64 + (((kk2*4+lq) ^ (l15&7))*8)];
#pragma unroll
        for (int nf2 = 0; nf2 < 8; ++nf2) {
          const int vr = nf2*16 + l15;
          bf16x8 vf = *(const bf16x8*)&Vs[vr*64 + ((kk2*4+lq) ^ (vr&7))*8];
          acc_o[nf2] = __builtin_amdgcn_mfma_f32_16x16x32_bf16(pf, vf, acc_o[nf2], 0, 0, 0);
        }
      }
    }

    const size_t ro = (size_t)(b*SEQ + qt*64 + w*16 + lq*4);
#pragma unroll
    for (int r = 0; r < 4; ++r) {
      const float inv = 1.0f / lsum[r];
#pragma unroll
      for (int nf2 = 0; nf2 < 8; ++nf2)
        out[(ro + r)*D_MODEL + h*HD + nf2*16 + l15] = f2bf(acc_o[nf2][r] * inv);
    }
    __syncthreads();
  }
}

// -----------------------------------------------------------------------------
extern "C" void kernel_launch(void* const* d_in, const int* in_sizes, int n_in,
                              void* d_out, int out_size, void* d_ws, size_t ws_size,
                              hipStream_t stream)
{
  (void)in_sizes; (void)n_in; (void)out_size; (void)ws_size;
  const float* x    = (const float*)d_in[0];
  const float* ln1s = (const float*)d_in[2];
  const float* ln1b = (const float*)d_in[3];
  const float* wq   = (const float*)d_in[4];
  const float* wk   = (const float*)d_in[5];
  const float* wv   = (const float*)d_in[6];
  const float* wo   = (const float*)d_in[7];
  const float* ln2s = (const float*)d_in[8];
  const float* ln2b = (const float*)d_in[9];
  const float* w1   = (const float*)d_in[10];
  const float* b1   = (const float*)d_in[11];
  const float* w2   = (const float*)d_in[12];
  const float* b2   = (const float*)d_in[13];
  float* out = (float*)d_out;

  char* ws = (char*)d_ws;
  constexpr size_t OFF_WQKV = 0;
  constexpr size_t OFF_WO   = OFF_WQKV + (size_t)3*D_MODEL*D_MODEL*2;
  constexpr size_t OFF_W1   = OFF_WO   + (size_t)D_MODEL*D_MODEL*2;
  constexpr size_t OFF_W2   = OFF_W1   + (size_t)D_FF*D_MODEL*2;
  constexpr size_t OFF_H    = OFF_W2   + (size_t)D_MODEL*D_FF*2;
  constexpr size_t OFF_QKV  = OFF_H    + (size_t)ROWS*D_MODEL*2;
  constexpr size_t OFF_VT   = OFF_QKV  + (size_t)ROWS*3*D_MODEL*2;
  constexpr size_t OFF_ATTN = OFF_VT   + (size_t)ROWS*D_MODEL*2;
  constexpr size_t OFF_X2   = OFF_ATTN + (size_t)ROWS*D_MODEL*2;

  u16*   wqkv_bt = (u16*)(ws + OFF_WQKV);   // [6144][2048]
  u16*   wo_bt   = (u16*)(ws + OFF_WO);     // [2048][2048]
  u16*   w1_bt   = (u16*)(ws + OFF_W1);     // [8192][2048]
  u16*   w2_bt   = (u16*)(ws + OFF_W2);     // [2048][8192]
  u16*   h_bf    = (u16*)(ws + OFF_H);      // [4096][2048]
  u16*   qkv     = (u16*)(ws + OFF_QKV);    // [4096][6144]
  u16*   vt      = (u16*)(ws + OFF_VT);     // [2][2048][2048]
  u16*   act     = qkv;                     // reuse qkv+vt region: [4096][8192]
  u16*   attn    = (u16*)(ws + OFF_ATTN);   // [4096][2048]
  float* x2      = (float*)(ws + OFF_X2);   // [4096][2048]

  const dim3 B256(256), B512(512);

  // ALL weight transposes in one launch (12288 blocks)
  transpose_all<<<dim3(12288), B256, 0, stream>>>(
      wq, wk, wv, wo, w1, w2, wqkv_bt, wo_bt, w1_bt, w2_bt);

  // LN1
  ln_bf16_kernel<<<ROWS, B256, 0, stream>>>(x, ln1s, ln1b, h_bf);
  // QKV: [4096,2048] x [2048,6144] -> bf16  (BN=128, grid 48x16 = 768)
  gemm8p<0,128><<<dim3(768), B512, 0, stream>>>(h_bf, wqkv_bt, qkv, nullptr, nullptr, 3*D_MODEL, D_MODEL, 48);
  // V -> V^T per (b,h)
  transpose_v<<<dim3(64,64,2), B256, 0, stream>>>(qkv, vt);
  // causal flash attention (paired q-tiles, grid 512)
  attn_kernel<<<dim3(BATCH*NH*16), B256, 0, stream>>>(qkv, vt, attn);
  // out projection + residual -> x2 fp32  (BN=128, grid 16x16 = 256)
  gemm8p<1,128><<<dim3(256), B512, 0, stream>>>(attn, wo_bt, (void*)x2, nullptr, x, D_MODEL, D_MODEL, 16);
  // LN2
  ln_bf16_kernel<<<ROWS, B256, 0, stream>>>(x2, ln2s, ln2b, h_bf);
  // FFN up + GELU  (BN=256, grid 32x16 = 512)
  gemm8p<2,256><<<dim3(512), B512, 0, stream>>>(h_bf, w1_bt, act, b1, nullptr, D_FF, D_MODEL, 32);
  // FFN down + bias + residual -> out fp32  (BN=128, grid 16x16 = 256)
  gemm8p<3,128><<<dim3(256), B512, 0, stream>>>(act, w2_bt, (void*)out, b2, x2, D_MODEL, D_FF, 16);
}